// Round 1
// 149.194 us; speedup vs baseline: 1.0089x; 1.0089x over previous
//
#include <hip/hip_runtime.h>

#define THREADS 256
#define GRID 2048
#define UNROLL 4   // 4 float4 per array per batch: 8 dwordx4 loads in flight/lane

// Kernel 1: per-block partial sums of the risk-aware MAE loss.
// percentiles is a uniform grid (linspace), so nearest-bin is analytic:
//   idx = clamp(rint((t - p0) * (P-1)/(pL - p0)), 0, P-1)
//
// Latency-hiding structure: fixed-UNROLL batches with all global loads
// issued before any consumption (compiler emits 8 global_load_dwordx4
// back-to-back per batch -> 128 B/lane in flight instead of 32 B).
__global__ __launch_bounds__(THREADS) void loss_partial_kernel(
    const float* __restrict__ outputs,
    const float* __restrict__ targets,
    const float* __restrict__ per,
    float* __restrict__ partials,
    int n, int P, float inv_maxbin) {

    // Uniform-grid parameters — wave-uniform scalar loads, L2-cached.
    const float p0 = per[0];
    const float pL = per[P - 1];
    const float inv_h = (float)(P - 1) / (pL - p0);
    const float kmax = (float)(P - 1);

    const int n4 = n >> 2;
    const float4* __restrict__ o4 = (const float4*)outputs;
    const float4* __restrict__ t4 = (const float4*)targets;

    const int tid = blockIdx.x * THREADS + threadIdx.x;
    const int stride = GRID * THREADS;   // compile-time constant

    float acc = 0.0f;

    int i = tid;

    // Main unrolled batches: issue all loads, then compute.
    for (; i + (UNROLL - 1) * stride < n4; i += UNROLL * stride) {
        float4 o[UNROLL], t[UNROLL];
        #pragma unroll
        for (int u = 0; u < UNROLL; ++u) {
            o[u] = o4[i + u * stride];
            t[u] = t4[i + u * stride];
        }
        #pragma unroll
        for (int u = 0; u < UNROLL; ++u) {
            #pragma unroll
            for (int c = 0; c < 4; ++c) {
                float tv = (c == 0) ? t[u].x : (c == 1) ? t[u].y : (c == 2) ? t[u].z : t[u].w;
                float ov = (c == 0) ? o[u].x : (c == 1) ? o[u].y : (c == 2) ? o[u].z : o[u].w;
                float k = rintf((tv - p0) * inv_h);
                k = fminf(fmaxf(k, 0.0f), kmax);        // clamp to [0, P-1]
                float f = (k + 1.0f) * inv_maxbin;      // factors = (idx+1)/P
                float e = tv - ov;                      // targets - outputs
                acc += fmaxf((f - 1.0f) * e, f * e);    // pinball loss
            }
        }
    }

    // Leftover float4 (when n4 not a multiple of UNROLL*stride).
    for (; i < n4; i += stride) {
        float4 o = o4[i];
        float4 t = t4[i];
        #pragma unroll
        for (int c = 0; c < 4; ++c) {
            float tv = (c == 0) ? t.x : (c == 1) ? t.y : (c == 2) ? t.z : t.w;
            float ov = (c == 0) ? o.x : (c == 1) ? o.y : (c == 2) ? o.z : o.w;
            float k = rintf((tv - p0) * inv_h);
            k = fminf(fmaxf(k, 0.0f), kmax);
            float f = (k + 1.0f) * inv_maxbin;
            float e = tv - ov;
            acc += fmaxf((f - 1.0f) * e, f * e);
        }
    }

    // Scalar tail (n % 4 != 0) — no-op for N = 16M, kept for safety.
    const int tail = n & 3;
    if (tail && blockIdx.x == 0 && threadIdx.x < tail) {
        int j = (n4 << 2) + threadIdx.x;
        float tv = targets[j];
        float ov = outputs[j];
        float k = rintf((tv - p0) * inv_h);
        k = fminf(fmaxf(k, 0.0f), kmax);
        float f = (k + 1.0f) * inv_maxbin;
        float e = tv - ov;
        acc += fmaxf((f - 1.0f) * e, f * e);
    }

    // Wave (64-lane) shuffle reduction.
    #pragma unroll
    for (int off = 32; off > 0; off >>= 1)
        acc += __shfl_down(acc, off, 64);

    __shared__ float lds[THREADS / 64];
    const int lane = threadIdx.x & 63;
    const int wave = threadIdx.x >> 6;
    if (lane == 0) lds[wave] = acc;
    __syncthreads();
    if (threadIdx.x == 0) {
        float s = 0.0f;
        #pragma unroll
        for (int w = 0; w < THREADS / 64; ++w) s += lds[w];
        partials[blockIdx.x] = s;
    }
}

// Kernel 2: reduce block partials in double, write mean as f32.
__global__ __launch_bounds__(THREADS) void finalize_kernel(
    const float* __restrict__ partials, int nblocks,
    float* __restrict__ out, double inv_n) {

    double acc = 0.0;
    for (int i = threadIdx.x; i < nblocks; i += blockDim.x)
        acc += (double)partials[i];

    #pragma unroll
    for (int off = 32; off > 0; off >>= 1)
        acc += __shfl_down(acc, off, 64);

    __shared__ double lds[THREADS / 64];
    const int lane = threadIdx.x & 63;
    const int wave = threadIdx.x >> 6;
    if (lane == 0) lds[wave] = acc;
    __syncthreads();
    if (threadIdx.x == 0) {
        double s = 0.0;
        #pragma unroll
        for (int w = 0; w < THREADS / 64; ++w) s += lds[w];
        out[0] = (float)(s * inv_n);
    }
}

extern "C" void kernel_launch(void* const* d_in, const int* in_sizes, int n_in,
                              void* d_out, int out_size, void* d_ws, size_t ws_size,
                              hipStream_t stream) {
    const float* outputs     = (const float*)d_in[0];
    const float* targets     = (const float*)d_in[1];
    const float* percentiles = (const float*)d_in[2];
    float* out = (float*)d_out;

    const int n = in_sizes[0];
    const int P = in_sizes[2];

    float* partials = (float*)d_ws;   // GRID floats, fully written before read

    loss_partial_kernel<<<GRID, THREADS, 0, stream>>>(
        outputs, targets, percentiles, partials, n, P, 1.0f / (float)P);

    finalize_kernel<<<1, THREADS, 0, stream>>>(
        partials, GRID, out, 1.0 / (double)n);
}